// Round 13
// baseline (82.688 us; speedup 1.0000x reference)
//
#include <hip/hip_runtime.h>
#include <stdint.h>

#define DIM     300
#define NBATCH  4096
#define NSUP    64      // N*S = 2*32 support cols
#define KP      320     // B K padded to 10*32
#define LSTR    328     // LDS row stride in ushorts for A and B tiles (656 B)
#define SMST    82      // padded sm tile x-stride (floats)
#define SMY     36      // per-channel y extent
#define GRID_G  256     // gemm blocks: 1 per CU
#define PPB     16      // batch panels per gemm block

typedef float f32x4 __attribute__((ext_vector_type(4)));
typedef short s16x8 __attribute__((ext_vector_type(8)));

static __device__ __forceinline__ unsigned bc(float x) { return __builtin_bit_cast(unsigned, x); }
static __device__ __forceinline__ float asf(unsigned u) { return __builtin_bit_cast(float, u); }
static __device__ __forceinline__ unsigned perm_hi(unsigned a, unsigned b) {
    return __builtin_amdgcn_perm(a, b, 0x07060302u);   // [a.hi16 : b.hi16]
}
static __device__ __forceinline__ unsigned short f2bf(float x) {   // RNE (prep only)
    unsigned u = bc(x);
    return (unsigned short)((u + 0x7FFFu + ((u >> 16) & 1u)) >> 16);
}
static __device__ __forceinline__ float bf2f(unsigned short h) { return asf((unsigned)h << 16); }

// ---------------- kernel 1: normalize support vectors -> bf16 hi/lo [64][320]
__global__ __launch_bounds__(64) void prep_kernel(
    const int* __restrict__ sidx, const float* __restrict__ emb,
    unsigned short* __restrict__ Bh, unsigned short* __restrict__ Bl) {
    const int j = blockIdx.x, l = threadIdx.x;
    const size_t tok = (size_t)sidx[j];
    const float* src = emb + tok * DIM;
    float e[5];
    #pragma unroll
    for (int c = 0; c < 5; ++c) {
        const int k = c * 64 + l;
        e[c] = (k < DIM) ? src[k] : 0.f;
    }
    float s = e[0]*e[0] + e[1]*e[1] + e[2]*e[2] + e[3]*e[3] + e[4]*e[4];
    #pragma unroll
    for (int m = 32; m >= 1; m >>= 1) s += __shfl_xor(s, m);
    const float rn = 1.f / fmaxf(sqrtf(s), 1e-8f);
    #pragma unroll
    for (int c = 0; c < 5; ++c) {
        const int k = c * 64 + l;
        const float v = (k < DIM) ? e[c] * rn : 0.f;
        const unsigned short h = f2bf(v);
        Bh[j * KP + k] = h;
        Bl[j * KP + k] = f2bf(v - bf2f(h));
    }
}

// ---------------- kernel 2: persistent gather-GEMM with FUSED tail.
// B resident in LDS; inner MFMA loop touches only LDS (no vmcnt) so next-panel
// HBM gathers (issued before the loop) fly under loop + tail phases.
// Per panel: MFMA+norms+softmax-epilogue -> conv1+gate+maxpool -> conv2+fc -> out.
__global__ __launch_bounds__(512) void gemm_kernel(
    const int* __restrict__ tokens, const float* __restrict__ emb,
    const unsigned short* __restrict__ Bh, const unsigned short* __restrict__ Bl,
    const float* __restrict__ c1w, const float* __restrict__ c1b,
    const float* __restrict__ c2w, const float* __restrict__ c2b,
    const float* __restrict__ f2w, const float* __restrict__ f2b,
    const float* __restrict__ fcw, const float* __restrict__ fcb,
    float* __restrict__ out) {

    __shared__ __attribute__((aligned(16))) unsigned short BhL[NSUP * LSTR]; // 42 KB
    __shared__ __attribute__((aligned(16))) unsigned short BlL[NSUP * LSTR]; // 42 KB
    __shared__ __attribute__((aligned(16))) unsigned short AhL[32 * LSTR];   // 21 KB
    __shared__ __attribute__((aligned(16))) unsigned short AlL[32 * LSTR];   // 21 KB
    __shared__ __attribute__((aligned(16))) float smP[34 * SMST];  // [xp=r+1][ch][yp=s+1]
    __shared__ __attribute__((aligned(16))) float pl1P[2 * 17 * 18];
    __shared__ __attribute__((aligned(16))) float norms[32];
    __shared__ __attribute__((aligned(16))) float scrP[16];  // [0..7]=se_w [8..15]=sv_w
    __shared__ float scr2[4];                                // fc partials

    const int tid = threadIdx.x;
    const int l = tid & 63;
    const int w = tid >> 6;
    const int c = l & 15, hq = l >> 4;
    const int rb = (w >> 2) * 16;
    const int cg = w & 3;
    const int ch = cg >> 1, sb = (cg & 1) * 16;
    const int bbase = blockIdx.x * PPB;
    const int oc = tid >> 8, ii = (tid >> 4) & 15, jj = tid & 15;

    // ---- one-time: stage B [64][320] -> LDS [64][328] (5120 16B chunks, 10/thread)
    #pragma unroll
    for (int m = 0; m < 10; ++m) {
        const int ci = tid + m * 512;            // 0..5119
        const int plane = ci / 2560;
        const int rem = ci - plane * 2560;
        const int rr = rem / 40, jc = rem - rr * 40;
        const uint4 v = *(const uint4*)((plane ? Bl : Bh) + rr * KP + jc * 8);
        *(uint4*)((plane ? BlL : BhL) + rr * LSTR + jc * 8) = v;
    }
    // ---- one-time: zero A K-pad (k=300..327)
    if (tid < 448) {
        const int row = tid / 14, q = tid - 14 * row;   // 14 uints = 28 ushorts
        ((unsigned*)AhL)[row * 164 + 150 + q] = 0u;
        ((unsigned*)AlL)[row * 164 + 150 + q] = 0u;
    }
    // ---- one-time: zero smP (borders stay 0; interior rewritten each panel)
    {
        const f32x4 z = {0.f, 0.f, 0.f, 0.f};
        ((f32x4*)smP)[tid] = z;
        if (tid < 697 - 512) ((f32x4*)smP)[512 + tid] = z;
    }
    // ---- one-time: zero pl1P borders (yp=0 row + xp=0 col, x2 channels)
    if (tid >= 446) {
        const int z2 = tid - 446;
        const int ic = z2 / 33, rm = z2 % 33;
        pl1P[ic * 306 + (rm < 17 ? rm : (rm - 16) * 18)] = 0.f;
    }

    // static staging chunk map: chunk ci = tid + 512*m over [32 rows][75 float4s]
    const int ci1 = tid + 512, ci2 = tid + 1024, ci3 = tid + 1536, ci4 = tid + 2048;
    const int r0 = tid / 75, j0 = tid - 75 * r0;
    const int r1 = ci1 / 75, j1 = ci1 - 75 * r1;
    const int r2 = ci2 / 75, j2 = ci2 - 75 * r2;
    const int r3 = ci3 / 75, j3 = ci3 - 75 * r3;
    const int r4 = ci4 / 75, j4 = ci4 - 75 * r4;
    const bool has4 = (ci4 < 2400);

    const int abase = (rb + c) * LSTR + hq * 8;
    const int bbl   = (cg * 16 + c) * LSTR + hq * 8;

    float4 st0, st1, st2, st3, st4;

    #define ISSUE_GATHER(TB)                                                        \
    {                                                                               \
        st0 = *(const float4*)(emb + (size_t)tokens[(TB) + r0] * DIM + j0 * 4);     \
        st1 = *(const float4*)(emb + (size_t)tokens[(TB) + r1] * DIM + j1 * 4);     \
        st2 = *(const float4*)(emb + (size_t)tokens[(TB) + r2] * DIM + j2 * 4);     \
        st3 = *(const float4*)(emb + (size_t)tokens[(TB) + r3] * DIM + j3 * 4);     \
        if (has4) st4 = *(const float4*)(emb + (size_t)tokens[(TB) + r4] * DIM + j4 * 4); \
    }

    #define STORE_CHUNK(ST, R, J)                                                   \
    {                                                                               \
        const unsigned u0 = bc(ST.x) + 0x8000u, u1 = bc(ST.y) + 0x8000u;            \
        const unsigned u2 = bc(ST.z) + 0x8000u, u3 = bc(ST.w) + 0x8000u;            \
        const float q0f = ST.x - asf(u0 & 0xffff0000u);                             \
        const float q1f = ST.y - asf(u1 & 0xffff0000u);                             \
        const float q2f = ST.z - asf(u2 & 0xffff0000u);                             \
        const float q3f = ST.w - asf(u3 & 0xffff0000u);                             \
        *(uint2*)(&AhL[(R) * LSTR + (J) * 4]) =                                     \
            uint2{perm_hi(u1, u0), perm_hi(u3, u2)};                                \
        *(uint2*)(&AlL[(R) * LSTR + (J) * 4]) =                                     \
            uint2{perm_hi(bc(q1f) + 0x8000u, bc(q0f) + 0x8000u),                    \
                  perm_hi(bc(q3f) + 0x8000u, bc(q2f) + 0x8000u)};                   \
    }

    #define STAGE_ALL()                                                             \
    {                                                                               \
        STORE_CHUNK(st0, r0, j0); STORE_CHUNK(st1, r1, j1);                         \
        STORE_CHUNK(st2, r2, j2); STORE_CHUNK(st3, r3, j3);                         \
        if (has4) STORE_CHUNK(st4, r4, j4);                                         \
    }

    // prologue: gather + stage panel 0
    ISSUE_GATHER(bbase * 32);
    STAGE_ALL();
    __syncthreads();   // A panel0 + B + pads + borders all ready

    #pragma unroll 1
    for (int p = 0; p < PPB; ++p) {
        // issue next panel's gathers NOW; nothing below touches vmcnt until STAGE
        if (p + 1 < PPB) ISSUE_GATHER((bbase + p + 1) * 32);
        __builtin_amdgcn_sched_barrier(0);

        // ---- pure-LDS MFMA loop + Gram norms
        f32x4 q0 = {0,0,0,0}, q1 = {0,0,0,0}, q2 = {0,0,0,0};
        f32x4 gv = {0,0,0,0}, g2 = {0,0,0,0};
        #pragma unroll
        for (int t = 0; t < 10; ++t) {
            const s16x8 ah = *(const s16x8*)(AhL + abase + t * 32);
            const s16x8 al = *(const s16x8*)(AlL + abase + t * 32);
            const s16x8 bh = *(const s16x8*)(BhL + bbl + t * 32);
            const s16x8 bl = *(const s16x8*)(BlL + bbl + t * 32);
            q0 = __builtin_amdgcn_mfma_f32_16x16x32_bf16(ah, bh, q0, 0, 0, 0);
            q1 = __builtin_amdgcn_mfma_f32_16x16x32_bf16(ah, bl, q1, 0, 0, 0);
            q2 = __builtin_amdgcn_mfma_f32_16x16x32_bf16(al, bh, q2, 0, 0, 0);
            gv = __builtin_amdgcn_mfma_f32_16x16x32_bf16(ah, ah, gv, 0, 0, 0);
            g2 = __builtin_amdgcn_mfma_f32_16x16x32_bf16(ah, al, g2, 0, 0, 0);
        }

        if (hq == (c >> 2)) {     // diagonal lanes own |row rb+c|^2
            const int q = c & 3;
            const float d1 = (q == 0) ? gv[0] : (q == 1) ? gv[1] : (q == 2) ? gv[2] : gv[3];
            const float d2 = (q == 0) ? g2[0] : (q == 1) ? g2[1] : (q == 2) ? g2[2] : g2[3];
            norms[rb + c] = d1 + 2.f * d2;
        }
        asm volatile("s_waitcnt lgkmcnt(0)" ::: "memory");   // intra-wave write->read
        const f32x4 n4 = *(const f32x4*)&norms[rb + hq * 4];
        // ---- epilogue: scale + smP write + fused softmax partials
        {
            const int s = sb + c;
            float se = 0.f, sv = 0.f;
            #pragma unroll
            for (int q = 0; q < 4; ++q) {
                const float rn = __builtin_amdgcn_rcpf(
                    fmaxf(__builtin_amdgcn_sqrtf(n4[q]), 1e-8f));
                const float v = (q0[q] + q1[q] + q2[q]) * rn;
                smP[(rb + hq * 4 + q + 1) * SMST + ch * SMY + (s + 1)] = v;
                const float e = __expf(v);      // |v| <= 1: no max-shift needed
                se += e; sv = fmaf(e, v, sv);
            }
            #pragma unroll
            for (int m = 32; m >= 1; m >>= 1) { se += __shfl_xor(se, m); sv += __shfl_xor(sv, m); }
            if (l == 0) { scrP[w] = se; scrP[8 + w] = sv; }
        }
        __syncthreads();   // BAR1: smP + softmax partials ready; A reads done

        // ---- conv1 partials (all threads) + gate + relu + maxpool -> pl1P
        {
            float pc[2][4] = {{0,0,0,0},{0,0,0,0}};
            #pragma unroll
            for (int ic = 0; ic < 2; ++ic) {
                float pp[4][4];
                #pragma unroll
                for (int a = 0; a < 4; ++a) {        // xp = 2jj+a, yp base 2ii
                    const int off = (2 * jj + a) * SMST + ic * SMY + 2 * ii;
                    const float2 v01 = *(const float2*)&smP[off];
                    const float2 v23 = *(const float2*)&smP[off + 2];
                    pp[a][0] = v01.x; pp[a][1] = v01.y; pp[a][2] = v23.x; pp[a][3] = v23.y;
                }
                #pragma unroll
                for (int py = 0; py < 2; ++py)
                #pragma unroll
                for (int px = 0; px < 2; ++px)
                #pragma unroll
                for (int dy = 0; dy < 3; ++dy)
                #pragma unroll
                for (int dx = 0; dx < 3; ++dx)
                    pc[ic][py * 2 + px] += c1w[(oc * 2 + ic) * 9 + dy * 3 + dx] *
                                           pp[px + dx][py + dy];
            }
            const f32x4 s0 = *(const f32x4*)&scrP[0];
            const f32x4 s1 = *(const f32x4*)&scrP[4];
            const f32x4 s2 = *(const f32x4*)&scrP[8];
            const f32x4 s3 = *(const f32x4*)&scrP[12];
            const float p0 = (s2.x + s2.y + s3.x + s3.y) / (s0.x + s0.y + s1.x + s1.y);
            const float p1 = (s2.z + s2.w + s3.z + s3.w) / (s0.z + s0.w + s1.z + s1.w);
            const float gg0 = 1.f / (1.f + __expf(-(f2w[0] * p0 + f2w[1] * p1 + f2b[0])));
            const float gg1 = 1.f / (1.f + __expf(-(f2w[2] * p0 + f2w[3] * p1 + f2b[1])));
            const float bias = c1b[oc];
            float mx = 0.f;    // relu folded
            #pragma unroll
            for (int i = 0; i < 4; ++i)
                mx = fmaxf(mx, bias + gg0 * pc[0][i] + gg1 * pc[1][i]);
            pl1P[oc * 306 + (ii + 1) * 18 + (jj + 1)] = mx;
        }
        __syncthreads();   // BAR2: pl1P ready

        // ---- waves 0-1: conv2(2x2,pad1)+relu+avgpool2 + fc partials
        if (w < 2) {
            const int oc2 = w, ii2 = l >> 3, jj2 = l & 7;
            float sum = 0.f;
            #pragma unroll
            for (int py = 0; py < 2; ++py)
            #pragma unroll
            for (int px = 0; px < 2; ++px) {
                const int y = 2 * ii2 + py, x = 2 * jj2 + px;
                float acc = c2b[oc2];
                #pragma unroll
                for (int ic = 0; ic < 2; ++ic)
                #pragma unroll
                for (int dy = 0; dy < 2; ++dy)
                #pragma unroll
                for (int dx = 0; dx < 2; ++dx)
                    acc += c2w[((oc2 * 2 + ic) * 2 + dy) * 2 + dx] *
                           pl1P[ic * 306 + (y + dy) * 18 + (x + dx)];
                sum += fmaxf(acc, 0.f);
            }
            const float val = 0.25f * sum;
            const int o = w * 64 + l;
            float t0 = val * fcw[o];
            float t1 = val * fcw[128 + o];
            #pragma unroll
            for (int m = 32; m >= 1; m >>= 1) { t0 += __shfl_xor(t0, m); t1 += __shfl_xor(t1, m); }
            if (l == 0) { scr2[w] = t0; scr2[2 + w] = t1; }
        }
        __syncthreads();   // BAR3: scr2 ready

        if (tid == 0) {
            const int b = bbase + p;
            out[b * 2 + 0] = fcb[0] + scr2[0] + scr2[1];
            out[b * 2 + 1] = fcb[1] + scr2[2] + scr2[3];
        }
        if (p + 1 < PPB) {
            // gathers have had loop + tail phases to land; stage next panel's A
            STAGE_ALL();
        }
        __syncthreads();   // BAR4: next panel's A ready; scr2/smP safe to rewrite
    }
    #undef STAGE_ALL
    #undef STORE_CHUNK
    #undef ISSUE_GATHER
}

extern "C" void kernel_launch(void* const* d_in, const int* in_sizes, int n_in,
                              void* d_out, int out_size, void* d_ws, size_t ws_size,
                              hipStream_t stream) {
    const int* tokens = (const int*)d_in[0];
    const int* sidx   = (const int*)d_in[1];
    const float* emb  = (const float*)d_in[2];
    const float* c1w  = (const float*)d_in[3];
    const float* c1b  = (const float*)d_in[4];
    const float* c2w  = (const float*)d_in[5];
    const float* c2b  = (const float*)d_in[6];
    const float* f2w  = (const float*)d_in[7];
    const float* f2b  = (const float*)d_in[8];
    const float* fcw  = (const float*)d_in[9];
    const float* fcb  = (const float*)d_in[10];

    // ws layout: [Bh 40 KiB][Bl 40 KiB]
    unsigned short* Bh = (unsigned short*)d_ws;
    unsigned short* Bl = Bh + NSUP * KP;

    prep_kernel<<<NSUP, 64, 0, stream>>>(sidx, emb, Bh, Bl);
    gemm_kernel<<<GRID_G, 512, 0, stream>>>(tokens, emb, Bh, Bl,
                                            c1w, c1b, c2w, c2b,
                                            f2w, f2b, fcw, fcb, (float*)d_out);
}